// Round 7
// baseline (310.530 us; speedup 1.0000x reference)
//
#include <hip/hip_runtime.h>
#include <math.h>

#define Bn 4
#define Cn 256
#define Hn 64
#define Wn 64
#define On 256
#define HWn 4096
#define Pn 16384   // B*H*W
#define Kc 2304    // 9*256

typedef _Float16 half8 __attribute__((ext_vector_type(8)));
typedef float floatx4 __attribute__((ext_vector_type(4)));

// ---------------------------------------------------------------------------
// fp32 NCHW -> f16 NHWC transpose (per batch). grid (HWn/32, Cn/32, B), block (32,8)
__global__ void k_transpose_f2h(const float* __restrict__ in, _Float16* __restrict__ out,
                                int R, int Cc) {
  __shared__ float tile[32][33];
  int b = blockIdx.z;
  int c0 = blockIdx.x * 32, r0 = blockIdx.y * 32;
  const float* ib = in + (size_t)b * R * Cc;
  _Float16* ob = out + (size_t)b * R * Cc;
  int tx = threadIdx.x, ty = threadIdx.y;
#pragma unroll
  for (int i = 0; i < 32; i += 8)
    tile[ty + i][tx] = ib[(size_t)(r0 + ty + i) * Cc + (c0 + tx)];
  __syncthreads();
#pragma unroll
  for (int i = 0; i < 32; i += 8)
    ob[(size_t)(c0 + ty + i) * R + (r0 + tx)] = (_Float16)tile[tx][ty + i];
}

// fp32 NHWC -> fp32 NCHW (final output)
__global__ void k_transpose(const float* __restrict__ in, float* __restrict__ out,
                            int R, int Cc) {
  __shared__ float tile[32][33];
  int b = blockIdx.z;
  int c0 = blockIdx.x * 32, r0 = blockIdx.y * 32;
  const float* ib = in + (size_t)b * R * Cc;
  float* ob = out + (size_t)b * R * Cc;
  int tx = threadIdx.x, ty = threadIdx.y;
#pragma unroll
  for (int i = 0; i < 32; i += 8)
    tile[ty + i][tx] = ib[(size_t)(r0 + ty + i) * Cc + (c0 + tx)];
  __syncthreads();
#pragma unroll
  for (int i = 0; i < 32; i += 8)
    ob[(size_t)(c0 + ty + i) * R + (r0 + tx)] = tile[tx][ty + i];
}

// ---------------------------------------------------------------------------
// Main-conv weights packed: chunk c = t*4 + ci/64; within chunk, group g=n>>4,
// kq: 1KB block where lane (quad,col) holds B[n=g*16+col][k=kq*32+quad*8+e].
__global__ void k_wt_pack(const float* __restrict__ w, _Float16* __restrict__ wtp) {
  int n = blockIdx.x;
  int ci = threadIdx.x;
  int g = n >> 4, col = n & 15;
  int cq = ci >> 6;
  int kk = ci & 63;
  int kq = kk >> 5;
  int k32 = kk & 31;
  int quad = k32 >> 3;
  int e = k32 & 7;
  const float* src = w + (size_t)n * 2304 + (size_t)ci * 9;
#pragma unroll
  for (int t = 0; t < 9; ++t) {
    int c = t * 4 + cq;
    size_t dst = ((size_t)((c * 16 + g) * 2 + kq)) * 512 + (quad * 16 + col) * 8 + e;
    wtp[dst] = (_Float16)src[t];
  }
}

// Offset-conv weights packed, N padded to 32 (2 groups): chunk c = t*4+cw is
// contiguous 2048 halves: ((c*2+g)*2+kq)*512 + (quad*16+col)*8 + e.
__global__ void k_wt_off_pack(const float* __restrict__ w, _Float16* __restrict__ wbop) {
  int n = blockIdx.x;     // 0..31
  int ci = threadIdx.x;   // 0..255
  int g = n >> 4, col = n & 15;
  int cw = ci >> 6;
  int r = ci & 63;
  int kq = r >> 5;
  int r2 = r & 31;
  int quad = r2 >> 3;
  int e = r2 & 7;
#pragma unroll
  for (int t = 0; t < 9; ++t) {
    int c = t * 4 + cw;
    size_t dst = ((size_t)((c * 2 + g) * 2 + kq)) * 512 + (quad * 16 + col) * 8 + e;
    wbop[dst] = (n < 27) ? (_Float16)w[((size_t)n * 256 + ci) * 9 + t] : (_Float16)0.f;
  }
}

// ---------------------------------------------------------------------------
// Offset conv via f16 MFMA — double-buffered LDS, ONE barrier per chunk.
// Mt=32, Nt=32, grid Pn/32=512 (2 blocks/CU), block 256 (4 waves = 2m x 2n).
// Order per chunk: write staged regs -> barrier -> issue next loads -> frags/MFMA.
// At the barrier nothing global is outstanding (writes already vmcnt-waited),
// so the syncthreads vmcnt(0) drain is free.
__global__ __launch_bounds__(256, 4) void k_off_mfma(const _Float16* __restrict__ xh,
                                                     const _Float16* __restrict__ wbop,
                                                     const float* __restrict__ boff,
                                                     float* __restrict__ om) {
  __shared__ __align__(16) _Float16 Ao[2][32][72];
  __shared__ __align__(16) _Float16 Bo[2][2048];

  int p0 = blockIdx.x * 32;
  int tid = threadIdx.x;
  int lane = tid & 63;
  int wave = tid >> 6;
  int mg = wave >> 1;
  int ng = wave & 1;
  int quad = lane >> 4;
  int col = lane & 15;

  int ar = tid >> 3;          // staging row 0..31
  int aci = (tid & 7) * 8;

  int p = p0 + ar;
  int bimg = p >> 12;
  int yx = p & 4095;
  int y = yx >> 6, x = yx & 63;

  half8 zero8;
#pragma unroll
  for (int e = 0; e < 8; ++e) zero8[e] = (_Float16)0.f;

  floatx4 acc = (floatx4){0.f, 0.f, 0.f, 0.f};

  half8 ga, gb;
  int abase = 0;
  bool avalid = false;

  // prologue: chunk 0 = tap 0 (dy=-1,dx=-1), ci-window 0
  {
    int sy = y - 1, sx = x - 1;
    avalid = (sy >= 0) & (sy < Hn) & (sx >= 0) & (sx < Wn);
    abase = (((bimg * Hn + (avalid ? sy : 0)) * Wn) + (avalid ? sx : 0)) * Cn;
    ga = zero8;
    if (avalid) ga = *(const half8*)(xh + (size_t)abase + aci);
    gb = *(const half8*)(wbop + (size_t)tid * 8);
  }

#pragma unroll
  for (int c = 0; c < 36; ++c) {
    int buf = c & 1;
    *(half8*)&Ao[buf][ar][aci] = ga;       // vmcnt-waits this chunk's loads
    *(half8*)&Bo[buf][tid * 8] = gb;
    __syncthreads();                        // drain free: nothing outstanding

    if (c < 35) {                           // issue next chunk's loads post-barrier
      int cn = c + 1;
      int tn = cn >> 2;
      int cin = (cn & 3) * 64;
      if ((cn & 3) == 0) {
        int sy = y + tn / 3 - 1;
        int sx = x + tn % 3 - 1;
        avalid = (sy >= 0) & (sy < Hn) & (sx >= 0) & (sx < Wn);
        abase = (((bimg * Hn + (avalid ? sy : 0)) * Wn) + (avalid ? sx : 0)) * Cn;
      }
      ga = zero8;
      if (avalid) ga = *(const half8*)(xh + (size_t)abase + cin + aci);
      gb = *(const half8*)(wbop + (size_t)cn * 2048 + tid * 8);
    }

    half8 af[2], bf[2];
#pragma unroll
    for (int kq = 0; kq < 2; ++kq) {
      af[kq] = *(const half8*)&Ao[buf][mg * 16 + col][kq * 32 + quad * 8];
      bf[kq] = *(const half8*)&Bo[buf][(ng * 2 + kq) * 512 + lane * 8];
    }
#pragma unroll
    for (int kq = 0; kq < 2; ++kq)
      acc = __builtin_amdgcn_mfma_f32_16x16x32_f16(af[kq], bf[kq], acc, 0, 0, 0);
  }

  int n = ng * 16 + col;
  if (n < 27) {
    float bb = boff[n];
#pragma unroll
    for (int r = 0; r < 4; ++r) {
      int pp = p0 + mg * 16 + quad * 4 + r;
      om[(size_t)pp * 32 + n] = acc[r] + bb;
    }
  }
}

// ---------------------------------------------------------------------------
// Coords: om[p][32] -> samp[p][9] = {int4 corner elem-offsets; float4 folded weights}
__global__ void k_coords(const float* __restrict__ om, float* __restrict__ samp) {
  int idx = blockIdx.x * 256 + threadIdx.x;   // Pn*9
  int k = idx % 9;
  int p = idx / 9;
  int bimg = p >> 12;
  int yx = p & 4095;
  int y = yx >> 6, x = yx & 63;

  const float* o = om + (size_t)p * 32;
  float dy = o[2 * k];
  float dx = o[2 * k + 1];
  float m = 1.f / (1.f + expf(-o[18 + k]));

  float ys = (float)(y + k / 3 - 1) + dy;
  float xs = (float)(x + k % 3 - 1) + dx;
  float y0f = floorf(ys), x0f = floorf(xs);
  float wy = ys - y0f, wx = xs - x0f;
  int y0 = (int)y0f, x0 = (int)x0f;
  int y1 = y0 + 1, x1 = x0 + 1;

  bool vy0 = (y0 >= 0) & (y0 < Hn);
  bool vy1 = (y1 >= 0) & (y1 < Hn);
  bool vx0 = (x0 >= 0) & (x0 < Wn);
  bool vx1 = (x1 >= 0) & (x1 < Wn);
  int y0c = min(max(y0, 0), Hn - 1), y1c = min(max(y1, 0), Hn - 1);
  int x0c = min(max(x0, 0), Wn - 1), x1c = min(max(x1, 0), Wn - 1);

  int base = bimg * HWn;
  int o00 = (base + y0c * Wn + x0c) * Cn;
  int o01 = (base + y0c * Wn + x1c) * Cn;
  int o10 = (base + y1c * Wn + x0c) * Cn;
  int o11 = (base + y1c * Wn + x1c) * Cn;

  float w00 = (vy0 && vx0) ? m * (1.f - wy) * (1.f - wx) : 0.f;
  float w01 = (vy0 && vx1) ? m * (1.f - wy) * wx : 0.f;
  float w10 = (vy1 && vx0) ? m * wy * (1.f - wx) : 0.f;
  float w11 = (vy1 && vx1) ? m * wy * wx : 0.f;

  float* s = samp + (size_t)idx * 8;
  ((int*)s)[0] = o00; ((int*)s)[1] = o01; ((int*)s)[2] = o10; ((int*)s)[3] = o11;
  s[4] = w00; s[5] = w01; s[6] = w10; s[7] = w11;
}

// ---------------------------------------------------------------------------
// Fused deformable-gather + f16 MFMA GEMM — double-buffered LDS, ONE barrier
// per chunk. Mt=64, Nt=256, 512 threads (8 waves = 2m x 4n), grid Pn/64=256.
// Per chunk: write As/Bs[c&1] from regs prefetched during chunk c-1 -> barrier
// (drain free) -> issue chunk c+1 loads -> ds_read frags -> 16 MFMA.
__global__ __launch_bounds__(512, 2) void k_gemm_main(
    const _Float16* __restrict__ xh, const float* __restrict__ samp,
    const _Float16* __restrict__ wtp, const float* __restrict__ bias,
    _Float16* __restrict__ outh, float* __restrict__ outf) {
  __shared__ __align__(16) _Float16 As[2][64][72];    // 18.4 KB
  __shared__ __align__(16) _Float16 Bs[2][16384];     // 64 KB

  int p0 = blockIdx.x * 64;
  int tid = threadIdx.x;       // 0..511
  int lane = tid & 63;
  int wave = tid >> 6;         // 0..7
  int quad = lane >> 4;
  int col = lane & 15;
  int mw = wave >> 2;          // 0..1 (32-row half)
  int nw = wave & 3;           // 0..3 (64-col group)

  int ar = tid >> 3;           // gather row 0..63
  int aci = (tid & 7) * 8;     // 8-channel segment

  const float* smp = samp + (size_t)(p0 + ar) * 72;

  float bj[4];
#pragma unroll
  for (int j = 0; j < 4; ++j) bj[j] = bias[(nw * 4 + j) * 16 + col];

  floatx4 acc[2][4];
#pragma unroll
  for (int i = 0; i < 2; ++i)
#pragma unroll
    for (int j = 0; j < 4; ++j) acc[i][j] = (floatx4){0.f, 0.f, 0.f, 0.f};

  half8 g00, g01, g10, g11;
  half8 bst[4];
  int4 ofs;
  float4 wv;

  // prologue: chunk 0
  ofs = *(const int4*)(smp);
  wv = *(const float4*)(smp + 4);
  g00 = *(const half8*)(xh + (size_t)ofs.x + aci);
  g01 = *(const half8*)(xh + (size_t)ofs.y + aci);
  g10 = *(const half8*)(xh + (size_t)ofs.z + aci);
  g11 = *(const half8*)(xh + (size_t)ofs.w + aci);
#pragma unroll
  for (int q = 0; q < 4; ++q)
    bst[q] = *(const half8*)(wtp + (size_t)(q * 512 + tid) * 8);

#pragma unroll
  for (int c = 0; c < 36; ++c) {
    int buf = c & 1;
    // stage this chunk from prefetch regs (vmcnt-waits those loads only)
    {
      _Float16 h00 = (_Float16)wv.x, h01 = (_Float16)wv.y;
      _Float16 h10 = (_Float16)wv.z, h11 = (_Float16)wv.w;
      half8 r;
#pragma unroll
      for (int e = 0; e < 8; ++e)
        r[e] = g00[e] * h00 + g01[e] * h01 + g10[e] * h10 + g11[e] * h11;
      *(half8*)&As[buf][ar][aci] = r;
    }
#pragma unroll
    for (int q = 0; q < 4; ++q)
      *(half8*)&Bs[buf][(q * 512 + tid) * 8] = bst[q];
    __syncthreads();   // only barrier per chunk; drain free (nothing outstanding)

    // issue chunk c+1 loads (window = this chunk's ds_reads + MFMAs + next write)
    if (c < 35) {
      int cn = c + 1;
      int tn = cn >> 2;
      int cin = (cn & 3) * 64;
      if ((cn & 3) == 0) {
        ofs = *(const int4*)(smp + tn * 8);
        wv = *(const float4*)(smp + tn * 8 + 4);
      }
      int ci = cin + aci;
      g00 = *(const half8*)(xh + (size_t)ofs.x + ci);
      g01 = *(const half8*)(xh + (size_t)ofs.y + ci);
      g10 = *(const half8*)(xh + (size_t)ofs.z + ci);
      g11 = *(const half8*)(xh + (size_t)ofs.w + ci);
      const _Float16* wsrc = wtp + (size_t)cn * 16384;
#pragma unroll
      for (int q = 0; q < 4; ++q)
        bst[q] = *(const half8*)(wsrc + (size_t)(q * 512 + tid) * 8);
    }

    half8 af[2][2];
#pragma unroll
    for (int kq = 0; kq < 2; ++kq)
#pragma unroll
      for (int i = 0; i < 2; ++i)
        af[kq][i] = *(const half8*)&As[buf][mw * 32 + i * 16 + col][kq * 32 + quad * 8];

    half8 bf[2][4];
#pragma unroll
    for (int kq = 0; kq < 2; ++kq)
#pragma unroll
      for (int j = 0; j < 4; ++j)
        bf[kq][j] = *(const half8*)&Bs[buf][((nw * 4 + j) * 2 + kq) * 512 + lane * 8];

#pragma unroll
    for (int kq = 0; kq < 2; ++kq)
#pragma unroll
      for (int i = 0; i < 2; ++i)
#pragma unroll
        for (int j = 0; j < 4; ++j)
          acc[i][j] = __builtin_amdgcn_mfma_f32_16x16x32_f16(
              af[kq][i], bf[kq][j], acc[i][j], 0, 0, 0);
  }

  // epilogue: bias + relu; f16 activations (or fp32 for the last layer)
#pragma unroll
  for (int i = 0; i < 2; ++i)
#pragma unroll
    for (int j = 0; j < 4; ++j) {
      int n = (nw * 4 + j) * 16 + col;
#pragma unroll
      for (int r = 0; r < 4; ++r) {
        int p = p0 + mw * 32 + i * 16 + quad * 4 + r;
        float v = fmaxf(acc[i][j][r] + bj[j], 0.f);
        if (outf) outf[(size_t)p * On + n] = v;
        else outh[(size_t)p * On + n] = (_Float16)v;
      }
    }
}

// ---------------------------------------------------------------------------
extern "C" void kernel_launch(void* const* d_in, const int* in_sizes, int n_in,
                              void* d_out, int out_size, void* d_ws, size_t ws_size,
                              hipStream_t stream) {
  (void)in_sizes; (void)n_in; (void)out_size; (void)ws_size;
  const float* x = (const float*)d_in[0];

  _Float16* act0h = (_Float16*)d_ws;                     // Pn*Cn f16
  _Float16* act1h = act0h + (size_t)Pn * Cn;             // Pn*Cn f16
  float* actf32   = (float*)(act1h + (size_t)Pn * Cn);   // Pn*On f32
  float* om       = actf32 + (size_t)Pn * On;            // Pn*32
  float* sampb    = om + (size_t)Pn * 32;                // Pn*9*8
  _Float16* wbop  = (_Float16*)(sampb + (size_t)Pn * 9 * 8);  // 36*2048 f16
  _Float16* wtp   = wbop + (size_t)36 * 2048;            // 256*Kc f16 (packed)

  dim3 tb(32, 8);
  k_transpose_f2h<<<dim3(HWn / 32, Cn / 32, Bn), tb, 0, stream>>>(x, act0h, Cn, HWn);

  _Float16* cur = act0h;
  _Float16* nxt = act1h;
  for (int l = 0; l < 3; ++l) {
    const float* w_off = (const float*)d_in[1 + l * 4];
    const float* b_off = (const float*)d_in[2 + l * 4];
    const float* w     = (const float*)d_in[3 + l * 4];
    const float* b     = (const float*)d_in[4 + l * 4];

    k_wt_off_pack<<<32, 256, 0, stream>>>(w_off, wbop);
    k_wt_pack<<<256, 256, 0, stream>>>(w, wtp);
    k_off_mfma<<<Pn / 32, 256, 0, stream>>>(cur, wbop, b_off, om);
    k_coords<<<(Pn * 9) / 256, 256, 0, stream>>>(om, sampb);
    k_gemm_main<<<Pn / 64, 512, 0, stream>>>(cur, sampb, wtp, b, nxt,
                                             (l == 2) ? actf32 : nullptr);
    _Float16* tswap = cur; cur = nxt; nxt = tswap;
  }
  k_transpose<<<dim3(On / 32, HWn / 32, Bn), tb, 0, stream>>>(actf32, (float*)d_out, HWn, On);
}

// Round 8
// 261.762 us; speedup vs baseline: 1.1863x; 1.1863x over previous
//
#include <hip/hip_runtime.h>
#include <math.h>

#define Bn 4
#define Cn 256
#define Hn 64
#define Wn 64
#define On 256
#define HWn 4096
#define Pn 16384   // B*H*W
#define Kc 2304    // 9*256

// s_waitcnt imm: vmcnt=63 (no wait), expcnt=7 (no wait), lgkmcnt=0 (drain LDS)
#define LGKM0 0xc07f

typedef _Float16 half8 __attribute__((ext_vector_type(8)));
typedef float floatx4 __attribute__((ext_vector_type(4)));

// ---------------------------------------------------------------------------
// fp32 NCHW -> f16 NHWC transpose (per batch). grid (HWn/32, Cn/32, B), block (32,8)
__global__ void k_transpose_f2h(const float* __restrict__ in, _Float16* __restrict__ out,
                                int R, int Cc) {
  __shared__ float tile[32][33];
  int b = blockIdx.z;
  int c0 = blockIdx.x * 32, r0 = blockIdx.y * 32;
  const float* ib = in + (size_t)b * R * Cc;
  _Float16* ob = out + (size_t)b * R * Cc;
  int tx = threadIdx.x, ty = threadIdx.y;
#pragma unroll
  for (int i = 0; i < 32; i += 8)
    tile[ty + i][tx] = ib[(size_t)(r0 + ty + i) * Cc + (c0 + tx)];
  __syncthreads();
#pragma unroll
  for (int i = 0; i < 32; i += 8)
    ob[(size_t)(c0 + ty + i) * R + (r0 + tx)] = (_Float16)tile[tx][ty + i];
}

// fp32 NHWC -> fp32 NCHW (final output)
__global__ void k_transpose(const float* __restrict__ in, float* __restrict__ out,
                            int R, int Cc) {
  __shared__ float tile[32][33];
  int b = blockIdx.z;
  int c0 = blockIdx.x * 32, r0 = blockIdx.y * 32;
  const float* ib = in + (size_t)b * R * Cc;
  float* ob = out + (size_t)b * R * Cc;
  int tx = threadIdx.x, ty = threadIdx.y;
#pragma unroll
  for (int i = 0; i < 32; i += 8)
    tile[ty + i][tx] = ib[(size_t)(r0 + ty + i) * Cc + (c0 + tx)];
  __syncthreads();
#pragma unroll
  for (int i = 0; i < 32; i += 8)
    ob[(size_t)(c0 + ty + i) * R + (r0 + tx)] = tile[tx][ty + i];
}

// ---------------------------------------------------------------------------
// Main-conv weights packed: chunk c = t*4 + ci/64; within chunk, group g=n>>4,
// kq: 1KB block where lane (quad,col) holds B[n=g*16+col][k=kq*32+quad*8+e].
__global__ void k_wt_pack(const float* __restrict__ w, _Float16* __restrict__ wtp) {
  int n = blockIdx.x;
  int ci = threadIdx.x;
  int g = n >> 4, col = n & 15;
  int cq = ci >> 6;
  int kk = ci & 63;
  int kq = kk >> 5;
  int k32 = kk & 31;
  int quad = k32 >> 3;
  int e = k32 & 7;
  const float* src = w + (size_t)n * 2304 + (size_t)ci * 9;
#pragma unroll
  for (int t = 0; t < 9; ++t) {
    int c = t * 4 + cq;
    size_t dst = ((size_t)((c * 16 + g) * 2 + kq)) * 512 + (quad * 16 + col) * 8 + e;
    wtp[dst] = (_Float16)src[t];
  }
}

// Offset-conv weights packed, N padded to 32 (2 groups): chunk c = t*4+cw is
// contiguous 2048 halves: ((c*2+g)*2+kq)*512 + (quad*16+col)*8 + e.
__global__ void k_wt_off_pack(const float* __restrict__ w, _Float16* __restrict__ wbop) {
  int n = blockIdx.x;     // 0..31
  int ci = threadIdx.x;   // 0..255
  int g = n >> 4, col = n & 15;
  int cw = ci >> 6;
  int r = ci & 63;
  int kq = r >> 5;
  int r2 = r & 31;
  int quad = r2 >> 3;
  int e = r2 & 7;
#pragma unroll
  for (int t = 0; t < 9; ++t) {
    int c = t * 4 + cw;
    size_t dst = ((size_t)((c * 2 + g) * 2 + kq)) * 512 + (quad * 16 + col) * 8 + e;
    wbop[dst] = (n < 27) ? (_Float16)w[((size_t)n * 256 + ci) * 9 + t] : (_Float16)0.f;
  }
}

// ---------------------------------------------------------------------------
// Offset conv via f16 MFMA — double-buffered LDS; K-loop barrier is raw
// s_barrier + lgkmcnt(0) ONLY (no vmcnt drain), so prefetch loads stay in
// flight across the barrier and VMEM never idles.
__global__ __launch_bounds__(256, 4) void k_off_mfma(const _Float16* __restrict__ xh,
                                                     const _Float16* __restrict__ wbop,
                                                     const float* __restrict__ boff,
                                                     float* __restrict__ om) {
  __shared__ __align__(16) _Float16 Ao[2][32][72];
  __shared__ __align__(16) _Float16 Bo[2][2048];

  int p0 = blockIdx.x * 32;
  int tid = threadIdx.x;
  int lane = tid & 63;
  int wave = tid >> 6;
  int mg = wave >> 1;
  int ng = wave & 1;
  int quad = lane >> 4;
  int col = lane & 15;

  int ar = tid >> 3;          // staging row 0..31
  int aci = (tid & 7) * 8;

  int p = p0 + ar;
  int bimg = p >> 12;
  int yx = p & 4095;
  int y = yx >> 6, x = yx & 63;

  half8 zero8;
#pragma unroll
  for (int e = 0; e < 8; ++e) zero8[e] = (_Float16)0.f;

  floatx4 acc = (floatx4){0.f, 0.f, 0.f, 0.f};

  half8 ga, gb;
  int abase = 0;
  bool avalid = false;

  // prologue: chunk 0 = tap 0 (dy=-1,dx=-1), ci-window 0
  {
    int sy = y - 1, sx = x - 1;
    avalid = (sy >= 0) & (sy < Hn) & (sx >= 0) & (sx < Wn);
    abase = (((bimg * Hn + (avalid ? sy : 0)) * Wn) + (avalid ? sx : 0)) * Cn;
    ga = zero8;
    if (avalid) ga = *(const half8*)(xh + (size_t)abase + aci);
    gb = *(const half8*)(wbop + (size_t)tid * 8);
  }

#pragma unroll
  for (int c = 0; c < 36; ++c) {
    int buf = c & 1;
    *(half8*)&Ao[buf][ar][aci] = ga;       // vmcnt-waits this chunk's loads only
    *(half8*)&Bo[buf][tid * 8] = gb;

    if (c < 35) {                           // issue next loads; they stay in
      int cn = c + 1;                       // flight across the barrier below
      int tn = cn >> 2;
      int cin = (cn & 3) * 64;
      if ((cn & 3) == 0) {
        int sy = y + tn / 3 - 1;
        int sx = x + tn % 3 - 1;
        avalid = (sy >= 0) & (sy < Hn) & (sx >= 0) & (sx < Wn);
        abase = (((bimg * Hn + (avalid ? sy : 0)) * Wn) + (avalid ? sx : 0)) * Cn;
      }
      ga = zero8;
      if (avalid) ga = *(const half8*)(xh + (size_t)abase + cin + aci);
      gb = *(const half8*)(wbop + (size_t)cn * 2048 + tid * 8);
    }

    __builtin_amdgcn_s_waitcnt(LGKM0);      // LDS writes visible; vmem NOT drained
    __builtin_amdgcn_s_barrier();

    half8 af[2], bf[2];
#pragma unroll
    for (int kq = 0; kq < 2; ++kq) {
      af[kq] = *(const half8*)&Ao[buf][mg * 16 + col][kq * 32 + quad * 8];
      bf[kq] = *(const half8*)&Bo[buf][(ng * 2 + kq) * 512 + lane * 8];
    }
#pragma unroll
    for (int kq = 0; kq < 2; ++kq)
      acc = __builtin_amdgcn_mfma_f32_16x16x32_f16(af[kq], bf[kq], acc, 0, 0, 0);
  }

  int n = ng * 16 + col;
  if (n < 27) {
    float bb = boff[n];
#pragma unroll
    for (int r = 0; r < 4; ++r) {
      int pp = p0 + mg * 16 + quad * 4 + r;
      om[(size_t)pp * 32 + n] = acc[r] + bb;
    }
  }
}

// ---------------------------------------------------------------------------
// Coords: om[p][32] -> samp[p][9] = {int4 corner elem-offsets; float4 folded weights}
__global__ void k_coords(const float* __restrict__ om, float* __restrict__ samp) {
  int idx = blockIdx.x * 256 + threadIdx.x;   // Pn*9
  int k = idx % 9;
  int p = idx / 9;
  int bimg = p >> 12;
  int yx = p & 4095;
  int y = yx >> 6, x = yx & 63;

  const float* o = om + (size_t)p * 32;
  float dy = o[2 * k];
  float dx = o[2 * k + 1];
  float m = 1.f / (1.f + expf(-o[18 + k]));

  float ys = (float)(y + k / 3 - 1) + dy;
  float xs = (float)(x + k % 3 - 1) + dx;
  float y0f = floorf(ys), x0f = floorf(xs);
  float wy = ys - y0f, wx = xs - x0f;
  int y0 = (int)y0f, x0 = (int)x0f;
  int y1 = y0 + 1, x1 = x0 + 1;

  bool vy0 = (y0 >= 0) & (y0 < Hn);
  bool vy1 = (y1 >= 0) & (y1 < Hn);
  bool vx0 = (x0 >= 0) & (x0 < Wn);
  bool vx1 = (x1 >= 0) & (x1 < Wn);
  int y0c = min(max(y0, 0), Hn - 1), y1c = min(max(y1, 0), Hn - 1);
  int x0c = min(max(x0, 0), Wn - 1), x1c = min(max(x1, 0), Wn - 1);

  int base = bimg * HWn;
  int o00 = (base + y0c * Wn + x0c) * Cn;
  int o01 = (base + y0c * Wn + x1c) * Cn;
  int o10 = (base + y1c * Wn + x0c) * Cn;
  int o11 = (base + y1c * Wn + x1c) * Cn;

  float w00 = (vy0 && vx0) ? m * (1.f - wy) * (1.f - wx) : 0.f;
  float w01 = (vy0 && vx1) ? m * (1.f - wy) * wx : 0.f;
  float w10 = (vy1 && vx0) ? m * wy * (1.f - wx) : 0.f;
  float w11 = (vy1 && vx1) ? m * wy * wx : 0.f;

  float* s = samp + (size_t)idx * 8;
  ((int*)s)[0] = o00; ((int*)s)[1] = o01; ((int*)s)[2] = o10; ((int*)s)[3] = o11;
  s[4] = w00; s[5] = w01; s[6] = w10; s[7] = w11;
}

// ---------------------------------------------------------------------------
// Fused deformable-gather + f16 MFMA GEMM — double-buffered LDS, ONE raw
// barrier (lgkmcnt(0) only) per chunk: prefetched global loads remain
// outstanding across the barrier, consumed by fine-grained vmcnt at the next
// chunk's LDS write. samp held in a 2-slot tap-parity scheme loaded 3-4
// chunks ahead so reading it never forces a vmcnt(0)-equivalent drain.
__global__ __launch_bounds__(512, 2) void k_gemm_main(
    const _Float16* __restrict__ xh, const float* __restrict__ samp,
    const _Float16* __restrict__ wtp, const float* __restrict__ bias,
    _Float16* __restrict__ outh, float* __restrict__ outf) {
  __shared__ __align__(16) _Float16 As[2][64][72];    // 18.4 KB
  __shared__ __align__(16) _Float16 Bs[2][16384];     // 64 KB

  int p0 = blockIdx.x * 64;
  int tid = threadIdx.x;       // 0..511
  int lane = tid & 63;
  int wave = tid >> 6;         // 0..7
  int quad = lane >> 4;
  int col = lane & 15;
  int mw = wave >> 2;          // 0..1 (32-row half)
  int nw = wave & 3;           // 0..3 (64-col group)

  int ar = tid >> 3;           // gather row 0..63
  int aci = (tid & 7) * 8;     // 8-channel segment

  const float* smp = samp + (size_t)(p0 + ar) * 72;

  float bj[4];
#pragma unroll
  for (int j = 0; j < 4; ++j) bj[j] = bias[(nw * 4 + j) * 16 + col];

  floatx4 acc[2][4];
#pragma unroll
  for (int i = 0; i < 2; ++i)
#pragma unroll
    for (int j = 0; j < 4; ++j) acc[i][j] = (floatx4){0.f, 0.f, 0.f, 0.f};

  half8 g00, g01, g10, g11;
  half8 bst[4];
  int4 ofsS[2];
  float4 wvS[2];

  // prologue: samp slot0 = tap0; issue chunk-0 loads
  ofsS[0] = *(const int4*)(smp);
  wvS[0] = *(const float4*)(smp + 4);
  g00 = *(const half8*)(xh + (size_t)ofsS[0].x + aci);
  g01 = *(const half8*)(xh + (size_t)ofsS[0].y + aci);
  g10 = *(const half8*)(xh + (size_t)ofsS[0].z + aci);
  g11 = *(const half8*)(xh + (size_t)ofsS[0].w + aci);
#pragma unroll
  for (int q = 0; q < 4; ++q)
    bst[q] = *(const half8*)(wtp + (size_t)(q * 512 + tid) * 8);

#pragma unroll
  for (int c = 0; c < 36; ++c) {
    int buf = c & 1;
    int t = c >> 2;
    // stage chunk c from prefetch regs (vmcnt-waits those loads only)
    {
      float4 wv = wvS[t & 1];
      _Float16 h00 = (_Float16)wv.x, h01 = (_Float16)wv.y;
      _Float16 h10 = (_Float16)wv.z, h11 = (_Float16)wv.w;
      half8 r;
#pragma unroll
      for (int e = 0; e < 8; ++e)
        r[e] = g00[e] * h00 + g01[e] * h01 + g10[e] * h10 + g11[e] * h11;
      *(half8*)&As[buf][ar][aci] = r;
    }
#pragma unroll
    for (int q = 0; q < 4; ++q)
      *(half8*)&Bs[buf][(q * 512 + tid) * 8] = bst[q];

    // issue chunk c+1 loads (remain in flight across the barrier)
    if (c < 35) {
      int cn = c + 1;
      int tn = cn >> 2;
      int cin = (cn & 3) * 64;
      int4 ofs = ofsS[tn & 1];   // slot loaded >=3 chunks ago: value ready
      int ci = cin + aci;
      g00 = *(const half8*)(xh + (size_t)ofs.x + ci);
      g01 = *(const half8*)(xh + (size_t)ofs.y + ci);
      g10 = *(const half8*)(xh + (size_t)ofs.z + ci);
      g11 = *(const half8*)(xh + (size_t)ofs.w + ci);
      const _Float16* wsrc = wtp + (size_t)cn * 16384;
#pragma unroll
      for (int q = 0; q < 4; ++q)
        bst[q] = *(const half8*)(wsrc + (size_t)(q * 512 + tid) * 8);
    }
    // refresh samp slot for tap t+1 (first address-use at c=4t+3)
    if ((c & 3) == 0 && t + 1 <= 8) {
      int tnl = t + 1;
      ofsS[tnl & 1] = *(const int4*)(smp + tnl * 8);
      wvS[tnl & 1] = *(const float4*)(smp + tnl * 8 + 4);
    }

    __builtin_amdgcn_s_waitcnt(LGKM0);   // LDS visible; vmem stays outstanding
    __builtin_amdgcn_s_barrier();

    half8 af[2][2];
#pragma unroll
    for (int kq = 0; kq < 2; ++kq)
#pragma unroll
      for (int i = 0; i < 2; ++i)
        af[kq][i] = *(const half8*)&As[buf][mw * 32 + i * 16 + col][kq * 32 + quad * 8];

    half8 bf[2][4];
#pragma unroll
    for (int kq = 0; kq < 2; ++kq)
#pragma unroll
      for (int j = 0; j < 4; ++j)
        bf[kq][j] = *(const half8*)&Bs[buf][((nw * 4 + j) * 2 + kq) * 512 + lane * 8];

#pragma unroll
    for (int kq = 0; kq < 2; ++kq)
#pragma unroll
      for (int i = 0; i < 2; ++i)
#pragma unroll
        for (int j = 0; j < 4; ++j)
          acc[i][j] = __builtin_amdgcn_mfma_f32_16x16x32_f16(
              af[kq][i], bf[kq][j], acc[i][j], 0, 0, 0);
  }

  // epilogue: bias + relu; f16 activations (or fp32 for the last layer)
#pragma unroll
  for (int i = 0; i < 2; ++i)
#pragma unroll
    for (int j = 0; j < 4; ++j) {
      int n = (nw * 4 + j) * 16 + col;
#pragma unroll
      for (int r = 0; r < 4; ++r) {
        int p = p0 + mw * 32 + i * 16 + quad * 4 + r;
        float v = fmaxf(acc[i][j][r] + bj[j], 0.f);
        if (outf) outf[(size_t)p * On + n] = v;
        else outh[(size_t)p * On + n] = (_Float16)v;
      }
    }
}

// ---------------------------------------------------------------------------
extern "C" void kernel_launch(void* const* d_in, const int* in_sizes, int n_in,
                              void* d_out, int out_size, void* d_ws, size_t ws_size,
                              hipStream_t stream) {
  (void)in_sizes; (void)n_in; (void)out_size; (void)ws_size;
  const float* x = (const float*)d_in[0];

  _Float16* act0h = (_Float16*)d_ws;                     // Pn*Cn f16
  _Float16* act1h = act0h + (size_t)Pn * Cn;             // Pn*Cn f16
  float* actf32   = (float*)(act1h + (size_t)Pn * Cn);   // Pn*On f32
  float* om       = actf32 + (size_t)Pn * On;            // Pn*32
  float* sampb    = om + (size_t)Pn * 32;                // Pn*9*8
  _Float16* wbop  = (_Float16*)(sampb + (size_t)Pn * 9 * 8);  // 36*2048 f16
  _Float16* wtp   = wbop + (size_t)36 * 2048;            // 256*Kc f16 (packed)

  dim3 tb(32, 8);
  k_transpose_f2h<<<dim3(HWn / 32, Cn / 32, Bn), tb, 0, stream>>>(x, act0h, Cn, HWn);

  _Float16* cur = act0h;
  _Float16* nxt = act1h;
  for (int l = 0; l < 3; ++l) {
    const float* w_off = (const float*)d_in[1 + l * 4];
    const float* b_off = (const float*)d_in[2 + l * 4];
    const float* w     = (const float*)d_in[3 + l * 4];
    const float* b     = (const float*)d_in[4 + l * 4];

    k_wt_off_pack<<<32, 256, 0, stream>>>(w_off, wbop);
    k_wt_pack<<<256, 256, 0, stream>>>(w, wtp);
    k_off_mfma<<<Pn / 32, 256, 0, stream>>>(cur, wbop, b_off, om);
    k_coords<<<(Pn * 9) / 256, 256, 0, stream>>>(om, sampb);
    k_gemm_main<<<Pn / 64, 512, 0, stream>>>(cur, sampb, wtp, b, nxt,
                                             (l == 2) ? actf32 : nullptr);
    _Float16* tswap = cur; cur = nxt; nxt = tswap;
  }
  k_transpose<<<dim3(On / 32, HWn / 32, Bn), tb, 0, stream>>>(actf32, (float*)d_out, HWn, On);
}

// Round 9
// 240.374 us; speedup vs baseline: 1.2919x; 1.0890x over previous
//
#include <hip/hip_runtime.h>
#include <math.h>

#define Bn 4
#define Cn 256
#define Hn 64
#define Wn 64
#define On 256
#define HWn 4096
#define Pn 16384   // B*H*W
#define Kc 2304    // 9*256

// s_waitcnt imm: vmcnt=63 (no wait), expcnt=7 (no wait), lgkmcnt=0 (drain LDS)
#define LGKM0 0xc07f

typedef _Float16 half8 __attribute__((ext_vector_type(8)));
typedef float floatx4 __attribute__((ext_vector_type(4)));

// ---------------------------------------------------------------------------
// fp32 NCHW -> f16 NHWC transpose (per batch). grid (HWn/32, Cn/32, B), block (32,8)
__global__ void k_transpose_f2h(const float* __restrict__ in, _Float16* __restrict__ out,
                                int R, int Cc) {
  __shared__ float tile[32][33];
  int b = blockIdx.z;
  int c0 = blockIdx.x * 32, r0 = blockIdx.y * 32;
  const float* ib = in + (size_t)b * R * Cc;
  _Float16* ob = out + (size_t)b * R * Cc;
  int tx = threadIdx.x, ty = threadIdx.y;
#pragma unroll
  for (int i = 0; i < 32; i += 8)
    tile[ty + i][tx] = ib[(size_t)(r0 + ty + i) * Cc + (c0 + tx)];
  __syncthreads();
#pragma unroll
  for (int i = 0; i < 32; i += 8)
    ob[(size_t)(c0 + ty + i) * R + (r0 + tx)] = (_Float16)tile[tx][ty + i];
}

// ---------------------------------------------------------------------------
// ONE kernel packs all 3 layers' weights (weights are activation-independent).
// blocks 0..767: main weights, layer l = bx>>8, n = bx&255 ->
//   wtp[l] chunk c = t*4+ci/64: 1KB block, lane(quad,col) holds
//   B[n=g*16+col][k=kq*32+quad*8+e].
// blocks 768..863: offset weights, layer l, oc row n (pad 27..31 = 0) ->
//   wbop[l] chunk c: 2048 halves ((c*2+g)*2+kq)*512 + (quad*16+col)*8 + e.
__global__ void k_pack_all(const float* __restrict__ w0, const float* __restrict__ w1,
                           const float* __restrict__ w2, const float* __restrict__ wo0,
                           const float* __restrict__ wo1, const float* __restrict__ wo2,
                           _Float16* __restrict__ wtp, _Float16* __restrict__ wbop) {
  int bx = blockIdx.x;
  int ci = threadIdx.x;
  if (bx < 768) {
    int l = bx >> 8;
    int n = bx & 255;
    const float* w = (l == 0) ? w0 : (l == 1) ? w1 : w2;
    _Float16* dst = wtp + (size_t)l * 256 * Kc;
    int g = n >> 4, col = n & 15;
    int cq = ci >> 6;
    int kk = ci & 63;
    int kq = kk >> 5;
    int k32 = kk & 31;
    int quad = k32 >> 3;
    int e = k32 & 7;
    const float* src = w + (size_t)n * 2304 + (size_t)ci * 9;
#pragma unroll
    for (int t = 0; t < 9; ++t) {
      int c = t * 4 + cq;
      size_t d = ((size_t)((c * 16 + g) * 2 + kq)) * 512 + (quad * 16 + col) * 8 + e;
      dst[d] = (_Float16)src[t];
    }
  } else {
    int b2 = bx - 768;
    int l = b2 >> 5;
    int n = b2 & 31;
    const float* w = (l == 0) ? wo0 : (l == 1) ? wo1 : wo2;
    _Float16* dst = wbop + (size_t)l * 36 * 2048;
    int g = n >> 4, col = n & 15;
    int cw = ci >> 6;
    int r = ci & 63;
    int kq = r >> 5;
    int r2 = r & 31;
    int quad = r2 >> 3;
    int e = r2 & 7;
#pragma unroll
    for (int t = 0; t < 9; ++t) {
      int c = t * 4 + cw;
      size_t d = ((size_t)((c * 2 + g) * 2 + kq)) * 512 + (quad * 16 + col) * 8 + e;
      dst[d] = (n < 27) ? (_Float16)w[((size_t)n * 256 + ci) * 9 + t] : (_Float16)0.f;
    }
  }
}

// ---------------------------------------------------------------------------
// Offset conv (f16 MFMA, dbuf LDS, lgkm-only barriers) + FUSED coords epilogue:
// om goes to LDS, samp computed and written in-kernel (k_coords eliminated).
__global__ __launch_bounds__(256, 4) void k_off_mfma(const _Float16* __restrict__ xh,
                                                     const _Float16* __restrict__ wbop,
                                                     const float* __restrict__ boff,
                                                     float* __restrict__ samp) {
  __shared__ __align__(16) _Float16 Ao[2][32][72];
  __shared__ __align__(16) _Float16 Bo[2][2048];
  __shared__ float omS[32][33];

  int p0 = blockIdx.x * 32;
  int tid = threadIdx.x;
  int lane = tid & 63;
  int wave = tid >> 6;
  int mg = wave >> 1;
  int ng = wave & 1;
  int quad = lane >> 4;
  int col = lane & 15;

  int ar = tid >> 3;          // staging row 0..31
  int aci = (tid & 7) * 8;

  int p = p0 + ar;
  int bimg = p >> 12;
  int yx = p & 4095;
  int y = yx >> 6, x = yx & 63;

  half8 zero8;
#pragma unroll
  for (int e = 0; e < 8; ++e) zero8[e] = (_Float16)0.f;

  floatx4 acc = (floatx4){0.f, 0.f, 0.f, 0.f};

  half8 ga, gb;
  int abase = 0;
  bool avalid = false;

  // prologue: chunk 0 = tap 0 (dy=-1,dx=-1), ci-window 0
  {
    int sy = y - 1, sx = x - 1;
    avalid = (sy >= 0) & (sy < Hn) & (sx >= 0) & (sx < Wn);
    abase = (((bimg * Hn + (avalid ? sy : 0)) * Wn) + (avalid ? sx : 0)) * Cn;
    ga = zero8;
    if (avalid) ga = *(const half8*)(xh + (size_t)abase + aci);
    gb = *(const half8*)(wbop + (size_t)tid * 8);
  }

#pragma unroll
  for (int c = 0; c < 36; ++c) {
    int buf = c & 1;
    *(half8*)&Ao[buf][ar][aci] = ga;       // vmcnt-waits this chunk's loads only
    *(half8*)&Bo[buf][tid * 8] = gb;

    if (c < 35) {                           // next loads stay in flight across barrier
      int cn = c + 1;
      int tn = cn >> 2;
      int cin = (cn & 3) * 64;
      if ((cn & 3) == 0) {
        int sy = y + tn / 3 - 1;
        int sx = x + tn % 3 - 1;
        avalid = (sy >= 0) & (sy < Hn) & (sx >= 0) & (sx < Wn);
        abase = (((bimg * Hn + (avalid ? sy : 0)) * Wn) + (avalid ? sx : 0)) * Cn;
      }
      ga = zero8;
      if (avalid) ga = *(const half8*)(xh + (size_t)abase + cin + aci);
      gb = *(const half8*)(wbop + (size_t)cn * 2048 + tid * 8);
    }

    __builtin_amdgcn_s_waitcnt(LGKM0);      // LDS visible; vmem NOT drained
    __builtin_amdgcn_s_barrier();

    half8 af[2], bf[2];
#pragma unroll
    for (int kq = 0; kq < 2; ++kq) {
      af[kq] = *(const half8*)&Ao[buf][mg * 16 + col][kq * 32 + quad * 8];
      bf[kq] = *(const half8*)&Bo[buf][(ng * 2 + kq) * 512 + lane * 8];
    }
#pragma unroll
    for (int kq = 0; kq < 2; ++kq)
      acc = __builtin_amdgcn_mfma_f32_16x16x32_f16(af[kq], bf[kq], acc, 0, 0, 0);
  }

  // om -> LDS
  int n = ng * 16 + col;
  if (n < 27) {
    float bb = boff[n];
#pragma unroll
    for (int r = 0; r < 4; ++r)
      omS[mg * 16 + quad * 4 + r][n] = acc[r] + bb;
  }
  __syncthreads();

  // fused coords: 32 px x 9 taps = 288 entries
  for (int e = tid; e < 288; e += 256) {
    int lp = e / 9;
    int k = e - lp * 9;
    int pp = p0 + lp;
    int bi = pp >> 12;
    int pyx = pp & 4095;
    int py = pyx >> 6, px = pyx & 63;

    float dy = omS[lp][2 * k];
    float dx = omS[lp][2 * k + 1];
    float m = 1.f / (1.f + expf(-omS[lp][18 + k]));

    float ys = (float)(py + k / 3 - 1) + dy;
    float xs = (float)(px + k % 3 - 1) + dx;
    float y0f = floorf(ys), x0f = floorf(xs);
    float wy = ys - y0f, wx = xs - x0f;
    int y0 = (int)y0f, x0 = (int)x0f;
    int y1 = y0 + 1, x1 = x0 + 1;

    bool vy0 = (y0 >= 0) & (y0 < Hn);
    bool vy1 = (y1 >= 0) & (y1 < Hn);
    bool vx0 = (x0 >= 0) & (x0 < Wn);
    bool vx1 = (x1 >= 0) & (x1 < Wn);
    int y0c = min(max(y0, 0), Hn - 1), y1c = min(max(y1, 0), Hn - 1);
    int x0c = min(max(x0, 0), Wn - 1), x1c = min(max(x1, 0), Wn - 1);

    int base = bi * HWn;
    int o00 = (base + y0c * Wn + x0c) * Cn;
    int o01 = (base + y0c * Wn + x1c) * Cn;
    int o10 = (base + y1c * Wn + x0c) * Cn;
    int o11 = (base + y1c * Wn + x1c) * Cn;

    float w00 = (vy0 && vx0) ? m * (1.f - wy) * (1.f - wx) : 0.f;
    float w01 = (vy0 && vx1) ? m * (1.f - wy) * wx : 0.f;
    float w10 = (vy1 && vx0) ? m * wy * (1.f - wx) : 0.f;
    float w11 = (vy1 && vx1) ? m * wy * wx : 0.f;

    float* s = samp + (size_t)(pp * 9 + k) * 8;
    ((int*)s)[0] = o00; ((int*)s)[1] = o01; ((int*)s)[2] = o10; ((int*)s)[3] = o11;
    s[4] = w00; s[5] = w01; s[6] = w10; s[7] = w11;
  }
}

// ---------------------------------------------------------------------------
// Fused deformable-gather + f16 MFMA GEMM — dbuf LDS, ONE lgkm-only barrier
// per chunk (prefetch loads stay outstanding across it). Last layer writes
// fp32 NCHW directly to d_out (final transpose kernel eliminated).
__global__ __launch_bounds__(512, 2) void k_gemm_main(
    const _Float16* __restrict__ xh, const float* __restrict__ samp,
    const _Float16* __restrict__ wtp, const float* __restrict__ bias,
    _Float16* __restrict__ outh, float* __restrict__ outf) {
  __shared__ __align__(16) _Float16 As[2][64][72];    // 18.4 KB
  __shared__ __align__(16) _Float16 Bs[2][16384];     // 64 KB

  int p0 = blockIdx.x * 64;
  int tid = threadIdx.x;       // 0..511
  int lane = tid & 63;
  int wave = tid >> 6;         // 0..7
  int quad = lane >> 4;
  int col = lane & 15;
  int mw = wave >> 2;          // 0..1 (32-row half)
  int nw = wave & 3;           // 0..3 (64-col group)

  int ar = tid >> 3;           // gather row 0..63
  int aci = (tid & 7) * 8;     // 8-channel segment

  const float* smp = samp + (size_t)(p0 + ar) * 72;

  float bj[4];
#pragma unroll
  for (int j = 0; j < 4; ++j) bj[j] = bias[(nw * 4 + j) * 16 + col];

  floatx4 acc[2][4];
#pragma unroll
  for (int i = 0; i < 2; ++i)
#pragma unroll
    for (int j = 0; j < 4; ++j) acc[i][j] = (floatx4){0.f, 0.f, 0.f, 0.f};

  half8 g00, g01, g10, g11;
  half8 bst[4];
  int4 ofsS[2];
  float4 wvS[2];

  // prologue: samp slot0 = tap0; issue chunk-0 loads
  ofsS[0] = *(const int4*)(smp);
  wvS[0] = *(const float4*)(smp + 4);
  g00 = *(const half8*)(xh + (size_t)ofsS[0].x + aci);
  g01 = *(const half8*)(xh + (size_t)ofsS[0].y + aci);
  g10 = *(const half8*)(xh + (size_t)ofsS[0].z + aci);
  g11 = *(const half8*)(xh + (size_t)ofsS[0].w + aci);
#pragma unroll
  for (int q = 0; q < 4; ++q)
    bst[q] = *(const half8*)(wtp + (size_t)(q * 512 + tid) * 8);

#pragma unroll
  for (int c = 0; c < 36; ++c) {
    int buf = c & 1;
    int t = c >> 2;
    // stage chunk c from prefetch regs (vmcnt-waits those loads only)
    {
      float4 wv = wvS[t & 1];
      _Float16 h00 = (_Float16)wv.x, h01 = (_Float16)wv.y;
      _Float16 h10 = (_Float16)wv.z, h11 = (_Float16)wv.w;
      half8 r;
#pragma unroll
      for (int e = 0; e < 8; ++e)
        r[e] = g00[e] * h00 + g01[e] * h01 + g10[e] * h10 + g11[e] * h11;
      *(half8*)&As[buf][ar][aci] = r;
    }
#pragma unroll
    for (int q = 0; q < 4; ++q)
      *(half8*)&Bs[buf][(q * 512 + tid) * 8] = bst[q];

    // issue chunk c+1 loads (remain in flight across the barrier)
    if (c < 35) {
      int cn = c + 1;
      int tn = cn >> 2;
      int cin = (cn & 3) * 64;
      int4 ofs = ofsS[tn & 1];   // slot loaded >=3 chunks ago: value ready
      int ci = cin + aci;
      g00 = *(const half8*)(xh + (size_t)ofs.x + ci);
      g01 = *(const half8*)(xh + (size_t)ofs.y + ci);
      g10 = *(const half8*)(xh + (size_t)ofs.z + ci);
      g11 = *(const half8*)(xh + (size_t)ofs.w + ci);
      const _Float16* wsrc = wtp + (size_t)cn * 16384;
#pragma unroll
      for (int q = 0; q < 4; ++q)
        bst[q] = *(const half8*)(wsrc + (size_t)(q * 512 + tid) * 8);
    }
    // refresh samp slot for tap t+1 (first address-use at c=4t+3)
    if ((c & 3) == 0 && t + 1 <= 8) {
      int tnl = t + 1;
      ofsS[tnl & 1] = *(const int4*)(smp + tnl * 8);
      wvS[tnl & 1] = *(const float4*)(smp + tnl * 8 + 4);
    }

    __builtin_amdgcn_s_waitcnt(LGKM0);   // LDS visible; vmem stays outstanding
    __builtin_amdgcn_s_barrier();

    half8 af[2][2];
#pragma unroll
    for (int kq = 0; kq < 2; ++kq)
#pragma unroll
      for (int i = 0; i < 2; ++i)
        af[kq][i] = *(const half8*)&As[buf][mw * 32 + i * 16 + col][kq * 32 + quad * 8];

    half8 bf[2][4];
#pragma unroll
    for (int kq = 0; kq < 2; ++kq)
#pragma unroll
      for (int j = 0; j < 4; ++j)
        bf[kq][j] = *(const half8*)&Bs[buf][((nw * 4 + j) * 2 + kq) * 512 + lane * 8];

#pragma unroll
    for (int kq = 0; kq < 2; ++kq)
#pragma unroll
      for (int i = 0; i < 2; ++i)
#pragma unroll
        for (int j = 0; j < 4; ++j)
          acc[i][j] = __builtin_amdgcn_mfma_f32_16x16x32_f16(
              af[kq][i], bf[kq][j], acc[i][j], 0, 0, 0);
  }

  // epilogue: bias + relu. Hidden layers: f16 NHWC. Last layer: fp32 NCHW
  // direct to d_out (float4: 4 consecutive p = 4 consecutive x).
#pragma unroll
  for (int i = 0; i < 2; ++i)
#pragma unroll
    for (int j = 0; j < 4; ++j) {
      int n = (nw * 4 + j) * 16 + col;
      if (outf) {
        int pb = p0 + mw * 32 + i * 16 + quad * 4;   // 4 consecutive pixels
        int bi = pb >> 12;
        int yx = pb & 4095;
        float4 v;
        v.x = fmaxf(acc[i][j][0] + bj[j], 0.f);
        v.y = fmaxf(acc[i][j][1] + bj[j], 0.f);
        v.z = fmaxf(acc[i][j][2] + bj[j], 0.f);
        v.w = fmaxf(acc[i][j][3] + bj[j], 0.f);
        *(float4*)(outf + ((size_t)(bi * On + n)) * HWn + yx) = v;
      } else {
#pragma unroll
        for (int r = 0; r < 4; ++r) {
          int p = p0 + mw * 32 + i * 16 + quad * 4 + r;
          float v = fmaxf(acc[i][j][r] + bj[j], 0.f);
          outh[(size_t)p * On + n] = (_Float16)v;
        }
      }
    }
}

// ---------------------------------------------------------------------------
extern "C" void kernel_launch(void* const* d_in, const int* in_sizes, int n_in,
                              void* d_out, int out_size, void* d_ws, size_t ws_size,
                              hipStream_t stream) {
  (void)in_sizes; (void)n_in; (void)out_size; (void)ws_size;
  const float* x = (const float*)d_in[0];

  _Float16* act0h = (_Float16*)d_ws;                     // Pn*Cn f16
  _Float16* act1h = act0h + (size_t)Pn * Cn;             // Pn*Cn f16
  float* sampb    = (float*)(act1h + (size_t)Pn * Cn);   // Pn*9*8 f32
  _Float16* wbop  = (_Float16*)(sampb + (size_t)Pn * 9 * 8);  // 3*36*2048 f16
  _Float16* wtp   = wbop + (size_t)3 * 36 * 2048;        // 3*256*Kc f16

  dim3 tb(32, 8);
  k_transpose_f2h<<<dim3(HWn / 32, Cn / 32, Bn), tb, 0, stream>>>(x, act0h, Cn, HWn);
  k_pack_all<<<864, 256, 0, stream>>>(
      (const float*)d_in[3], (const float*)d_in[7], (const float*)d_in[11],
      (const float*)d_in[1], (const float*)d_in[5], (const float*)d_in[9],
      wtp, wbop);

  _Float16* cur = act0h;
  _Float16* nxt = act1h;
  for (int l = 0; l < 3; ++l) {
    const float* b_off = (const float*)d_in[2 + l * 4];
    const float* b     = (const float*)d_in[4 + l * 4];

    k_off_mfma<<<Pn / 32, 256, 0, stream>>>(cur, wbop + (size_t)l * 36 * 2048, b_off, sampb);
    k_gemm_main<<<Pn / 64, 512, 0, stream>>>(cur, sampb, wtp + (size_t)l * 256 * Kc, b, nxt,
                                             (l == 2) ? (float*)d_out : nullptr);
    _Float16* tswap = cur; cur = nxt; nxt = tswap;
  }
}

// Round 10
// 235.309 us; speedup vs baseline: 1.3197x; 1.0215x over previous
//
#include <hip/hip_runtime.h>
#include <math.h>

#define Bn 4
#define Cn 256
#define Hn 64
#define Wn 64
#define On 256
#define HWn 4096
#define Pn 16384   // B*H*W
#define Kc 2304    // 9*256

// s_waitcnt imm: vmcnt=63 (no wait), expcnt=7 (no wait), lgkmcnt=0 (drain LDS)
#define LGKM0 0xc07f

typedef _Float16 half8 __attribute__((ext_vector_type(8)));
typedef float floatx4 __attribute__((ext_vector_type(4)));

// ---------------------------------------------------------------------------
// ONE init kernel: blocks 0..4095 = fp32 NCHW -> f16 NHWC transpose;
// 4096..4863 = main-weight pack (layer l = (bx-4096)>>8, n = &255);
// 4864..4959 = offset-weight pack (layer l = (bx-4864)>>5, oc = &31).
__global__ void k_init(const float* __restrict__ x, _Float16* __restrict__ act0,
                       const float* __restrict__ w0, const float* __restrict__ w1,
                       const float* __restrict__ w2, const float* __restrict__ wo0,
                       const float* __restrict__ wo1, const float* __restrict__ wo2,
                       _Float16* __restrict__ wtp, _Float16* __restrict__ wbop) {
  int bx = blockIdx.x;
  int tid = threadIdx.x;
  if (bx < 4096) {
    // transpose tile: R=Cn rows, Cc=HWn cols; out[b][hw][ch] = in[b][ch][hw]
    __shared__ float tile[32][33];
    int cx = bx & 127, cy = (bx >> 7) & 7, b = bx >> 10;
    int c0 = cx * 32, r0 = cy * 32;
    int tx = tid & 31, ty = tid >> 5;
    const float* ib = x + (size_t)b * Cn * HWn;
    _Float16* ob = act0 + (size_t)b * Cn * HWn;
#pragma unroll
    for (int i = 0; i < 32; i += 8)
      tile[ty + i][tx] = ib[(size_t)(r0 + ty + i) * HWn + (c0 + tx)];
    __syncthreads();
#pragma unroll
    for (int i = 0; i < 32; i += 8)
      ob[(size_t)(c0 + ty + i) * Cn + (r0 + tx)] = (_Float16)tile[tx][ty + i];
  } else if (bx < 4864) {
    int b2 = bx - 4096;
    int l = b2 >> 8;
    int n = b2 & 255;
    const float* w = (l == 0) ? w0 : (l == 1) ? w1 : w2;
    _Float16* dst = wtp + (size_t)l * 256 * Kc;
    int g = n >> 4, col = n & 15;
    int cq = tid >> 6;
    int kk = tid & 63;
    int kq = kk >> 5;
    int k32 = kk & 31;
    int quad = k32 >> 3;
    int e = k32 & 7;
    const float* src = w + (size_t)n * 2304 + (size_t)tid * 9;
#pragma unroll
    for (int t = 0; t < 9; ++t) {
      int c = t * 4 + cq;
      size_t d = ((size_t)((c * 16 + g) * 2 + kq)) * 512 + (quad * 16 + col) * 8 + e;
      dst[d] = (_Float16)src[t];
    }
  } else {
    int b3 = bx - 4864;
    int l = b3 >> 5;
    int n = b3 & 31;
    const float* w = (l == 0) ? wo0 : (l == 1) ? wo1 : wo2;
    _Float16* dst = wbop + (size_t)l * 36 * 2048;
    int g = n >> 4, col = n & 15;
    int cw = tid >> 6;
    int r = tid & 63;
    int kq = r >> 5;
    int r2 = r & 31;
    int quad = r2 >> 3;
    int e = r2 & 7;
#pragma unroll
    for (int t = 0; t < 9; ++t) {
      int c = t * 4 + cw;
      size_t d = ((size_t)((c * 2 + g) * 2 + kq)) * 512 + (quad * 16 + col) * 8 + e;
      dst[d] = (n < 27) ? (_Float16)w[((size_t)n * 256 + tid) * 9 + t] : (_Float16)0.f;
    }
  }
}

// ---------------------------------------------------------------------------
// FUSED layer kernel: one block = 64 pixels, 512 threads (8 waves).
// Phase 1: offset conv (M=64, N=32, K=2304) via MFMA, dbuf LDS, lgkm-only
//          barriers; om kept in LDS; coords -> sampS in LDS.
// Phase 2: deformable-gather main GEMM (M=64, N=256) as in R8, taps from LDS.
// LDS: As dbuf 18.4K + Bs dbuf 64K (phase 1 carves Bo/omS from it) + sampS 18K.
__global__ __launch_bounds__(512) void k_layer(
    const _Float16* __restrict__ xh,
    const _Float16* __restrict__ wbop, const float* __restrict__ boff,
    const _Float16* __restrict__ wtp, const float* __restrict__ bias,
    _Float16* __restrict__ outh, float* __restrict__ outf) {
  __shared__ __align__(16) _Float16 As[2][64][72];    // 18.4 KB
  __shared__ __align__(16) _Float16 Bs[2][16384];     // 64 KB
  __shared__ __align__(16) float sampS[64][9][8];     // 18 KB

  int p0 = blockIdx.x * 64;
  int tid = threadIdx.x;       // 0..511
  int lane = tid & 63;
  int wave = tid >> 6;         // 0..7
  int quad = lane >> 4;
  int col = lane & 15;

  int ar = tid >> 3;           // staging/gather row 0..63
  int aci = (tid & 7) * 8;     // 8-channel segment

  int p = p0 + ar;
  int bimg = p >> 12;
  int yx = p & 4095;
  int y = yx >> 6, x = yx & 63;

  half8 zero8;
#pragma unroll
  for (int e = 0; e < 8; ++e) zero8[e] = (_Float16)0.f;

  // early prefetch of phase-2 chunk-0 B (independent of everything)
  half8 bst[4];
#pragma unroll
  for (int q = 0; q < 4; ++q)
    bst[q] = *(const half8*)(wtp + (size_t)(q * 512 + tid) * 8);

  // ================= phase 1: offset conv =================
  _Float16* Bo0 = &Bs[0][0];
  _Float16* Bo1 = &Bs[0][2048];
  float* omS = (float*)&Bs[1][0];   // [64][33]

  int mi = wave >> 1;   // 0..3 (16-row group)
  int ng = wave & 1;    // 0..1 (16-col group)

  floatx4 acc1 = (floatx4){0.f, 0.f, 0.f, 0.f};
  half8 ga, gb = zero8;
  int abase = 0;
  bool avalid = false;
  {
    int sy = y - 1, sx = x - 1;
    avalid = (sy >= 0) & (sy < Hn) & (sx >= 0) & (sx < Wn);
    abase = (((bimg * Hn + (avalid ? sy : 0)) * Wn) + (avalid ? sx : 0)) * Cn;
    ga = zero8;
    if (avalid) ga = *(const half8*)(xh + (size_t)abase + aci);
    if (tid < 256) gb = *(const half8*)(wbop + (size_t)tid * 8);
  }

#pragma unroll
  for (int c = 0; c < 36; ++c) {
    int buf = c & 1;
    *(half8*)&As[buf][ar][aci] = ga;
    if (tid < 256) *(half8*)&(buf ? Bo1 : Bo0)[tid * 8] = gb;

    if (c < 35) {                        // next loads stay in flight across barrier
      int cn = c + 1;
      int tn = cn >> 2;
      int cin = (cn & 3) * 64;
      if ((cn & 3) == 0) {
        int sy = y + tn / 3 - 1;
        int sx = x + tn % 3 - 1;
        avalid = (sy >= 0) & (sy < Hn) & (sx >= 0) & (sx < Wn);
        abase = (((bimg * Hn + (avalid ? sy : 0)) * Wn) + (avalid ? sx : 0)) * Cn;
      }
      ga = zero8;
      if (avalid) ga = *(const half8*)(xh + (size_t)abase + cin + aci);
      if (tid < 256) gb = *(const half8*)(wbop + (size_t)cn * 2048 + tid * 8);
    }

    __builtin_amdgcn_s_waitcnt(LGKM0);   // LDS visible; vmem NOT drained
    __builtin_amdgcn_s_barrier();

    const _Float16* BoB = buf ? Bo1 : Bo0;
#pragma unroll
    for (int kq = 0; kq < 2; ++kq) {
      half8 af = *(const half8*)&As[buf][mi * 16 + col][kq * 32 + quad * 8];
      half8 bf = *(const half8*)&BoB[(ng * 2 + kq) * 512 + lane * 8];
      acc1 = __builtin_amdgcn_mfma_f32_16x16x32_f16(af, bf, acc1, 0, 0, 0);
    }
  }

  // om -> LDS
  {
    int n1 = ng * 16 + col;
    if (n1 < 27) {
      float bb = boff[n1];
#pragma unroll
      for (int r = 0; r < 4; ++r)
        omS[(mi * 16 + quad * 4 + r) * 33 + n1] = acc1[r] + bb;
    }
  }
  __syncthreads();

  // fused coords: 64 px x 9 taps = 576 entries -> sampS (LDS)
  for (int e = tid; e < 576; e += 512) {
    int lp = e / 9;
    int k = e - lp * 9;
    int pp = p0 + lp;
    int bi = pp >> 12;
    int pyx = pp & 4095;
    int py = pyx >> 6, px = pyx & 63;

    float dy = omS[lp * 33 + 2 * k];
    float dx = omS[lp * 33 + 2 * k + 1];
    float m = 1.f / (1.f + expf(-omS[lp * 33 + 18 + k]));

    float ys = (float)(py + k / 3 - 1) + dy;
    float xs = (float)(px + k % 3 - 1) + dx;
    float y0f = floorf(ys), x0f = floorf(xs);
    float wy = ys - y0f, wx = xs - x0f;
    int y0 = (int)y0f, x0 = (int)x0f;
    int y1 = y0 + 1, x1 = x0 + 1;

    bool vy0 = (y0 >= 0) & (y0 < Hn);
    bool vy1 = (y1 >= 0) & (y1 < Hn);
    bool vx0 = (x0 >= 0) & (x0 < Wn);
    bool vx1 = (x1 >= 0) & (x1 < Wn);
    int y0c = min(max(y0, 0), Hn - 1), y1c = min(max(y1, 0), Hn - 1);
    int x0c = min(max(x0, 0), Wn - 1), x1c = min(max(x1, 0), Wn - 1);

    int base = bi * HWn;
    float* s = &sampS[lp][k][0];
    ((int*)s)[0] = (base + y0c * Wn + x0c) * Cn;
    ((int*)s)[1] = (base + y0c * Wn + x1c) * Cn;
    ((int*)s)[2] = (base + y1c * Wn + x0c) * Cn;
    ((int*)s)[3] = (base + y1c * Wn + x1c) * Cn;
    s[4] = (vy0 && vx0) ? m * (1.f - wy) * (1.f - wx) : 0.f;
    s[5] = (vy0 && vx1) ? m * (1.f - wy) * wx : 0.f;
    s[6] = (vy1 && vx0) ? m * wy * (1.f - wx) : 0.f;
    s[7] = (vy1 && vx1) ? m * wy * wx : 0.f;
  }
  __syncthreads();

  // ================= phase 2: deformable main GEMM =================
  int mw = wave >> 2;          // 0..1 (32-row half)
  int nw = wave & 3;           // 0..3 (64-col group)

  float bj[4];
#pragma unroll
  for (int j = 0; j < 4; ++j) bj[j] = bias[(nw * 4 + j) * 16 + col];

  floatx4 acc[2][4];
#pragma unroll
  for (int i = 0; i < 2; ++i)
#pragma unroll
    for (int j = 0; j < 4; ++j) acc[i][j] = (floatx4){0.f, 0.f, 0.f, 0.f};

  half8 g00, g01, g10, g11;
  int4 ofsS[2];
  float4 wvS[2];

  // prologue: tap0 from LDS; issue chunk-0 gathers (bst already in flight)
  ofsS[0] = *(const int4*)&sampS[ar][0][0];
  wvS[0] = *(const float4*)&sampS[ar][0][4];
  g00 = *(const half8*)(xh + (size_t)ofsS[0].x + aci);
  g01 = *(const half8*)(xh + (size_t)ofsS[0].y + aci);
  g10 = *(const half8*)(xh + (size_t)ofsS[0].z + aci);
  g11 = *(const half8*)(xh + (size_t)ofsS[0].w + aci);

#pragma unroll
  for (int c = 0; c < 36; ++c) {
    int buf = c & 1;
    int t = c >> 2;
    // stage chunk c from prefetch regs (vmcnt-waits those loads only)
    {
      float4 wv = wvS[t & 1];
      _Float16 h00 = (_Float16)wv.x, h01 = (_Float16)wv.y;
      _Float16 h10 = (_Float16)wv.z, h11 = (_Float16)wv.w;
      half8 r;
#pragma unroll
      for (int e = 0; e < 8; ++e)
        r[e] = g00[e] * h00 + g01[e] * h01 + g10[e] * h10 + g11[e] * h11;
      *(half8*)&As[buf][ar][aci] = r;
    }
#pragma unroll
    for (int q = 0; q < 4; ++q)
      *(half8*)&Bs[buf][(q * 512 + tid) * 8] = bst[q];

    // issue chunk c+1 loads (remain in flight across the barrier)
    if (c < 35) {
      int cn = c + 1;
      int tn = cn >> 2;
      int cin = (cn & 3) * 64;
      int4 ofs = ofsS[tn & 1];
      int ci = cin + aci;
      g00 = *(const half8*)(xh + (size_t)ofs.x + ci);
      g01 = *(const half8*)(xh + (size_t)ofs.y + ci);
      g10 = *(const half8*)(xh + (size_t)ofs.z + ci);
      g11 = *(const half8*)(xh + (size_t)ofs.w + ci);
      const _Float16* wsrc = wtp + (size_t)cn * 16384;
#pragma unroll
      for (int q = 0; q < 4; ++q)
        bst[q] = *(const half8*)(wsrc + (size_t)(q * 512 + tid) * 8);
    }
    // refresh samp slot for tap t+1 from LDS (first address-use at c=4t+3)
    if ((c & 3) == 0 && t + 1 <= 8) {
      int tnl = t + 1;
      ofsS[tnl & 1] = *(const int4*)&sampS[ar][tnl][0];
      wvS[tnl & 1] = *(const float4*)&sampS[ar][tnl][4];
    }

    __builtin_amdgcn_s_waitcnt(LGKM0);   // LDS visible; vmem stays outstanding
    __builtin_amdgcn_s_barrier();

    half8 af[2][2];
#pragma unroll
    for (int kq = 0; kq < 2; ++kq)
#pragma unroll
      for (int i = 0; i < 2; ++i)
        af[kq][i] = *(const half8*)&As[buf][mw * 32 + i * 16 + col][kq * 32 + quad * 8];

    half8 bf[2][4];
#pragma unroll
    for (int kq = 0; kq < 2; ++kq)
#pragma unroll
      for (int j = 0; j < 4; ++j)
        bf[kq][j] = *(const half8*)&Bs[buf][((nw * 4 + j) * 2 + kq) * 512 + lane * 8];

#pragma unroll
    for (int kq = 0; kq < 2; ++kq)
#pragma unroll
      for (int i = 0; i < 2; ++i)
#pragma unroll
        for (int j = 0; j < 4; ++j)
          acc[i][j] = __builtin_amdgcn_mfma_f32_16x16x32_f16(
              af[kq][i], bf[kq][j], acc[i][j], 0, 0, 0);
  }

  // epilogue: bias + relu. Hidden layers: f16 NHWC. Last layer: fp32 NCHW
  // direct to d_out (float4: 4 consecutive p = 4 consecutive x).
#pragma unroll
  for (int i = 0; i < 2; ++i)
#pragma unroll
    for (int j = 0; j < 4; ++j) {
      int n = (nw * 4 + j) * 16 + col;
      if (outf) {
        int pb = p0 + mw * 32 + i * 16 + quad * 4;
        int bi = pb >> 12;
        int pyx = pb & 4095;
        float4 v;
        v.x = fmaxf(acc[i][j][0] + bj[j], 0.f);
        v.y = fmaxf(acc[i][j][1] + bj[j], 0.f);
        v.z = fmaxf(acc[i][j][2] + bj[j], 0.f);
        v.w = fmaxf(acc[i][j][3] + bj[j], 0.f);
        *(float4*)(outf + ((size_t)(bi * On + n)) * HWn + pyx) = v;
      } else {
#pragma unroll
        for (int r = 0; r < 4; ++r) {
          int pp = p0 + mw * 32 + i * 16 + quad * 4 + r;
          float v = fmaxf(acc[i][j][r] + bj[j], 0.f);
          outh[(size_t)pp * On + n] = (_Float16)v;
        }
      }
    }
}

// ---------------------------------------------------------------------------
extern "C" void kernel_launch(void* const* d_in, const int* in_sizes, int n_in,
                              void* d_out, int out_size, void* d_ws, size_t ws_size,
                              hipStream_t stream) {
  (void)in_sizes; (void)n_in; (void)out_size; (void)ws_size;
  const float* x = (const float*)d_in[0];

  _Float16* act0h = (_Float16*)d_ws;                     // Pn*Cn f16
  _Float16* act1h = act0h + (size_t)Pn * Cn;             // Pn*Cn f16
  _Float16* wbop  = act1h + (size_t)Pn * Cn;             // 3*36*2048 f16
  _Float16* wtp   = wbop + (size_t)3 * 36 * 2048;        // 3*256*Kc f16

  k_init<<<4960, 256, 0, stream>>>(
      x, act0h,
      (const float*)d_in[3], (const float*)d_in[7], (const float*)d_in[11],
      (const float*)d_in[1], (const float*)d_in[5], (const float*)d_in[9],
      wtp, wbop);

  _Float16* cur = act0h;
  _Float16* nxt = act1h;
  for (int l = 0; l < 3; ++l) {
    const float* b_off = (const float*)d_in[2 + l * 4];
    const float* b     = (const float*)d_in[4 + l * 4];
    k_layer<<<Pn / 64, 512, 0, stream>>>(
        cur, wbop + (size_t)l * 36 * 2048, b_off,
        wtp + (size_t)l * 256 * Kc, b, nxt,
        (l == 2) ? (float*)d_out : nullptr);
    _Float16* tswap = cur; cur = nxt; nxt = tswap;
  }
}